// Round 6
// baseline (909.832 us; speedup 1.0000x reference)
//
#include <hip/hip_runtime.h>

// QLORA: Y = X @ (W_nf4*c1*c2) + (X @ L1) @ L2
// M=8192, K=4096, N=4096, RANK=16.
// R9 changes vs R8:
//  - GEMM K-loop converted to the verified "minimum 2-phase" pipeline:
//    BK=32 double-buffered (32KB LDS, same occupancy), stage(t+1) issued
//    BEFORE compute(t), ONE __syncthreads per K-step (its full vmcnt/lgkm
//    drain provides all ordering -- no counted vmcnt). Loads now fly across
//    the whole compute phase instead of being drained immediately.
//  - GEMM split into 8 M-eighths (~42us each): any prep dispatch >=45us now
//    surfaces in the profile top-5 with counters (R8 showed none >=166us).
//  - prep kernels single-launch again (R8's doubling was the diagnostic),
//    bodies unchanged.

#define M_ROWS 8192
#define K_DIM  4096
#define N_OUT  4096
#define CVT_BLOCKS 16384        // M*K/8/256
#define WP_BLOCKS  4096         // (N/64)*(K/64)

typedef float  f32x16 __attribute__((ext_vector_type(16)));
typedef float  f32x4  __attribute__((ext_vector_type(4)));
typedef __bf16 bf16x8 __attribute__((ext_vector_type(8)));
typedef unsigned short ushort8v __attribute__((ext_vector_type(8)));

__device__ float          Tg[(size_t)M_ROWS * 16];   // T = X@L1, fp32
__device__ unsigned short L1t[16 * K_DIM];           // L1^T, bf16
__device__ unsigned short L2t[N_OUT * 16];           // L2^T, bf16

__device__ __forceinline__ unsigned short f2bf(float f) {
    __bf16 h = (__bf16)f;                       // native v_cvt (RNE)
    union { __bf16 h; unsigned short u; } v; v.h = h;
    return v.u;
}

// ---------------------------------------------------------- X fp32 -> bf16
__global__ __launch_bounds__(256) void cvt_kernel(
        const float* __restrict__ X, ushort8v* __restrict__ Xh) {
    size_t tid = (size_t)blockIdx.x * 256 + threadIdx.x;
    const float4* xp = (const float4*)X;
    float4 a = xp[tid * 2];
    float4 b = xp[tid * 2 + 1];
    ushort8v o;
    o[0] = f2bf(a.x); o[1] = f2bf(a.y); o[2] = f2bf(a.z); o[3] = f2bf(a.w);
    o[4] = f2bf(b.x); o[5] = f2bf(b.y); o[6] = f2bf(b.z); o[7] = f2bf(b.w);
    Xh[tid] = o;
}

// -------------------- W' = W_nf4*c1*c2, transposed store via LDS 64x64 tile
__global__ __launch_bounds__(256) void wprep_kernel(
        const float* __restrict__ Wnf4, const float* __restrict__ c1p,
        const float* __restrict__ c2,   unsigned short* __restrict__ Wt) {
    __shared__ unsigned short tile[64][72];   // [n][k], pad 8 keeps 16B align
    const int t  = threadIdx.x;
    const int wb = blockIdx.x;
    const int n0 = (wb & 63) * 64;
    const int k0 = (wb >> 6) * 64;
    const float c1 = *c1p;

    #pragma unroll
    for (int i = 0; i < 4; ++i) {
        int idx = i * 1024 + t * 4;
        int k = idx >> 6, n4 = idx & 63;
        size_t g = (size_t)(k0 + k) * N_OUT + n0 + n4;
        float4 w = *(const float4*)&Wnf4[g];
        float4 s = *(const float4*)&c2[g];
        tile[n4    ][k] = f2bf(w.x * c1 * s.x);
        tile[n4 + 1][k] = f2bf(w.y * c1 * s.y);
        tile[n4 + 2][k] = f2bf(w.z * c1 * s.z);
        tile[n4 + 3][k] = f2bf(w.w * c1 * s.w);
    }
    __syncthreads();

    #pragma unroll
    for (int i = 0; i < 2; ++i) {
        int task = i * 256 + t;
        int n = task >> 3, k8 = (task & 7) * 8;
        ushort8v o = *(const ushort8v*)&tile[n][k8];
        *(ushort8v*)&Wt[(size_t)(n0 + n) * K_DIM + k0 + k8] = o;
    }
}

// ------------------- tiny transposes: L1 -> L1t (bf16), L2 -> L2t (bf16)
__global__ __launch_bounds__(256) void lorap_kernel(
        const float* __restrict__ L1, const float* __restrict__ L2) {
    const int idx = blockIdx.x * 256 + threadIdx.x;
    if (idx < K_DIM) {                       // L1t, thread = one k
        const float4* lp = (const float4*)&L1[(size_t)idx * 16];
        float4 r0 = lp[0], r1 = lp[1], r2 = lp[2], r3 = lp[3];
        float v[16] = {r0.x, r0.y, r0.z, r0.w, r1.x, r1.y, r1.z, r1.w,
                       r2.x, r2.y, r2.z, r2.w, r3.x, r3.y, r3.z, r3.w};
        #pragma unroll
        for (int r = 0; r < 16; ++r)
            L1t[(size_t)r * K_DIM + idx] = f2bf(v[r]);
    } else {                                 // L2t, thread = one n
        const int n = idx - K_DIM;
        ushort8v a, b;
        #pragma unroll
        for (int r = 0; r < 8; ++r) a[r] = f2bf(L2[(size_t)r * N_OUT + n]);
        #pragma unroll
        for (int r = 0; r < 8; ++r) b[r] = f2bf(L2[(size_t)(r + 8) * N_OUT + n]);
        *(ushort8v*)&L2t[(size_t)n * 16]     = a;
        *(ushort8v*)&L2t[(size_t)n * 16 + 8] = b;
    }
}

// ------------------------------------------------- T = Xh @ L1  (8192 x 16)
__global__ __launch_bounds__(256) void xl1_kernel(const __bf16* __restrict__ Xh) {
    __shared__ float red[4][256];
    const int m0 = blockIdx.x * 16;
    const int t = threadIdx.x, wv = t >> 6, lane = t & 63;
    const int l15 = lane & 15, l4 = lane >> 4;
    const __bf16* ap = Xh + (size_t)(m0 + l15) * K_DIM + wv * 1024 + l4 * 8;
    const __bf16* bp = (const __bf16*)L1t + (size_t)l15 * K_DIM + wv * 1024 + l4 * 8;
    f32x4 acc = {};
    #pragma unroll 8
    for (int k = 0; k < 1024; k += 32) {
        bf16x8 a = *(const bf16x8*)(ap + k);
        bf16x8 b = *(const bf16x8*)(bp + k);
        acc = __builtin_amdgcn_mfma_f32_16x16x32_bf16(a, b, acc, 0, 0, 0);
    }
    #pragma unroll
    for (int r = 0; r < 4; ++r) red[wv][(l4 * 4 + r) * 16 + l15] = acc[r];
    __syncthreads();
    if (wv == 0) {
        #pragma unroll
        for (int r = 0; r < 4; ++r) {
            int e = (l4 * 4 + r) * 16 + l15;
            Tg[(size_t)(m0 + l4 * 4 + r) * 16 + l15] =
                red[0][e] + red[1][e] + red[2][e] + red[3][e];
        }
    }
}

// ----------------------------------------------------------------- bf16 GEMM
// C[M][N] = A[M][K]*Bt[N][K]^T + T@L2t^T ; 128x128 tile, BK=32 double-buffered
// "minimum 2-phase": stage(t+1) issued before compute(t); ONE __syncthreads
// per K-step (full drain = all ordering). 4 waves, verified R5 swizzle.
// m_base: M-eighth offset (kernel launched 8x, 1024 rows each).
#define COMPUTE(B) do { \
    bf16x8 af[2][2], bfr[2][2]; \
    _Pragma("unroll") for (int mt = 0; mt < 2; ++mt) \
      _Pragma("unroll") for (int ks = 0; ks < 2; ++ks) { \
        int row = wm + mt * 32 + l32; \
        int slot = (2 * ks + half) ^ rsw; \
        af[mt][ks] = *(const bf16x8*)(&As[B][0] + row * 32 + slot * 8); \
      } \
    _Pragma("unroll") for (int nt = 0; nt < 2; ++nt) \
      _Pragma("unroll") for (int ks = 0; ks < 2; ++ks) { \
        int row = wn + nt * 32 + l32; \
        int slot = (2 * ks + half) ^ rsw; \
        bfr[nt][ks] = *(const bf16x8*)(&Bs[B][0] + row * 32 + slot * 8); \
      } \
    _Pragma("unroll") for (int ks = 0; ks < 2; ++ks) \
      _Pragma("unroll") for (int mt = 0; mt < 2; ++mt) \
        _Pragma("unroll") for (int nt = 0; nt < 2; ++nt) \
          acc[mt][nt] = __builtin_amdgcn_mfma_f32_32x32x16_bf16( \
              af[mt][ks], bfr[nt][ks], acc[mt][nt], 0, 0, 0); \
} while (0)

__global__ __launch_bounds__(256) void gemm_bt_kernel(
        const __bf16* __restrict__ A, const __bf16* __restrict__ Bt,
        float* __restrict__ C, int m_base) {
    __shared__ __bf16 As[2][128 * 32];   // 2 x 8 KB
    __shared__ __bf16 Bs[2][128 * 32];   // 2 x 8 KB

    const int t    = threadIdx.x;
    const int w    = t >> 6;
    const int lane = t & 63;
    const int half = lane >> 5;       // 0..1
    const int l32  = lane & 31;

    const int m0   = m_base + blockIdx.y * 128;
    const int n0   = blockIdx.x * 128;

    const int wm   = (w >> 1) * 64;
    const int wn   = (w & 1) * 64;

    // staging source permutation: lane l -> row l>>2,
    // phys slot l&3 holds logical slot (l&3)^((l>>3)&3)
    const int srow = lane >> 2;
    const int scol = ((lane & 3) ^ ((lane >> 3) & 3)) * 8;
    // read-side swizzle: (row>>1)&3 with row = base32 + l32
    const int rsw = (l32 >> 1) & 3;

    // stage one BK=32 tile pair into buffer b (A + B, 2 loads each per wave)
    auto stg = [&](int b, int kb) {
        #pragma unroll
        for (int j = 0; j < 2; ++j) {
            int row = w * 32 + j * 16 + srow;
            const __bf16* ga = A + (size_t)(m0 + row) * K_DIM + kb + scol;
            __builtin_amdgcn_global_load_lds(
                (const __attribute__((address_space(1))) unsigned int*)ga,
                (__attribute__((address_space(3))) unsigned int*)
                    (&As[b][0] + (w * 32 + j * 16) * 32),
                16, 0, 0);
            const __bf16* gb = Bt + (size_t)(n0 + row) * K_DIM + kb + scol;
            __builtin_amdgcn_global_load_lds(
                (const __attribute__((address_space(1))) unsigned int*)gb,
                (__attribute__((address_space(3))) unsigned int*)
                    (&Bs[b][0] + (w * 32 + j * 16) * 32),
                16, 0, 0);
        }
    };

    f32x16 acc[2][2] = {};

    stg(0, 0);                                   // prologue
    for (int kb = 0; kb < K_DIM; kb += 32) {
        const int cur = (kb >> 5) & 1;
        __syncthreads();                         // drains stage(kb) + prev reads
        if (kb + 32 < K_DIM) stg(cur ^ 1, kb + 32);  // fly across compute
        COMPUTE(cur);
    }

    // ---- LoRA epilogue (verified in R5): acc += T(128x16) @ L2t^T, K=16.
    {
        bf16x8 afl[2], bfl[2];
        #pragma unroll
        for (int mt = 0; mt < 2; ++mt) {
            const float* tp = Tg + (size_t)(m0 + wm + mt * 32 + l32) * 16 + half * 8;
            float4 p0 = *(const float4*)tp;
            float4 p1 = *(const float4*)(tp + 4);
            afl[mt][0] = (__bf16)p0.x; afl[mt][1] = (__bf16)p0.y;
            afl[mt][2] = (__bf16)p0.z; afl[mt][3] = (__bf16)p0.w;
            afl[mt][4] = (__bf16)p1.x; afl[mt][5] = (__bf16)p1.y;
            afl[mt][6] = (__bf16)p1.z; afl[mt][7] = (__bf16)p1.w;
        }
        #pragma unroll
        for (int nt = 0; nt < 2; ++nt)
            bfl[nt] = *(const bf16x8*)((const __bf16*)L2t +
                        (size_t)(n0 + wn + nt * 32 + l32) * 16 + half * 8);
        #pragma unroll
        for (int mt = 0; mt < 2; ++mt)
            #pragma unroll
            for (int nt = 0; nt < 2; ++nt)
                acc[mt][nt] = __builtin_amdgcn_mfma_f32_32x32x16_bf16(
                    afl[mt], bfl[nt], acc[mt][nt], 0, 0, 0);
    }

    // epilogue: C/D 32x32 layout col=lane&31, row=(reg&3)+8*(reg>>2)+4*half
    #pragma unroll
    for (int mt = 0; mt < 2; ++mt)
        #pragma unroll
        for (int nt = 0; nt < 2; ++nt) {
            int col = n0 + wn + nt * 32 + l32;
            #pragma unroll
            for (int reg = 0; reg < 16; ++reg) {
                int row = m0 + wm + mt * 32 + (reg & 3) + 8 * (reg >> 2) + 4 * half;
                C[(size_t)row * N_OUT + col] = acc[mt][nt][reg];
            }
        }
}

extern "C" void kernel_launch(void* const* d_in, const int* in_sizes, int n_in,
                              void* d_out, int out_size, void* d_ws, size_t ws_size,
                              hipStream_t stream) {
    const float* X    = (const float*)d_in[0];
    const float* Wnf4 = (const float*)d_in[1];
    const float* c1   = (const float*)d_in[2];   // scalar
    const float* c2   = (const float*)d_in[3];
    const float* L1   = (const float*)d_in[4];
    const float* L2   = (const float*)d_in[5];
    float* Y = (float*)d_out;

    unsigned short* Xh = (unsigned short*)d_ws;                                       // 64 MB
    unsigned short* Wt = (unsigned short*)((char*)d_ws + (size_t)M_ROWS * K_DIM * 2); // 32 MB

    cvt_kernel<<<CVT_BLOCKS, 256, 0, stream>>>(X, (ushort8v*)Xh);
    wprep_kernel<<<WP_BLOCKS, 256, 0, stream>>>(Wnf4, c1, c2, Wt);
    lorap_kernel<<<32, 256, 0, stream>>>(L1, L2);
    xl1_kernel<<<M_ROWS / 16, 256, 0, stream>>>((const __bf16*)Xh);

    // GEMM in 8 M-eighths: top-5 visibility threshold drops to ~42us so any
    // prep dispatch >=45us surfaces with counters.
    for (int q = 0; q < 8; ++q)
        gemm_bt_kernel<<<dim3(N_OUT / 128, 8), 256, 0, stream>>>(
            (const __bf16*)Xh, (const __bf16*)Wt, Y, q * 1024);
}

// Round 7
// 720.514 us; speedup vs baseline: 1.2628x; 1.2628x over previous
//
#include <hip/hip_runtime.h>

// QLORA: Y = X @ (W_nf4*c1*c2) + (X @ L1) @ L2
// M=8192, K=4096, N=4096, RANK=16.
// R10 changes vs R9:
//  - Found the hidden ~300us: harness re-poison fill (512MiB @ ~78us/iter,
//    86% HBM peak) -- fixed overhead, also flushes L3 each iter (preps run
//    cold every iteration; R8's +42us doubling delta was the L3-hot copy).
//  - GEMM: revert to the R7/R8-verified BK=64 2-barrier body. Quarter-split
//    (512 blocks = 2 blocks/CU) instead of R9's eighth-split (1 block/CU
//    killed cross-block overlap: MfmaUtil 37->16.8, eighth=77us).
//  - cvt+wprep+xl1 fused into ONE dispatch (independent: xl1 reads fp32 X
//    directly; lorap launched first provides L1t). Its duration = the true
//    prep total, now above the ~86us top-5 threshold -> counters next round.

#define M_ROWS 8192
#define K_DIM  4096
#define N_OUT  4096
#define CVT_BLOCKS 16384        // M*K/8/256
#define WP_BLOCKS  4096         // (N/64)*(K/64)
#define XL1_BLOCKS 512          // M/16
#define PREP_BLOCKS (CVT_BLOCKS + WP_BLOCKS + XL1_BLOCKS)

typedef float  f32x16 __attribute__((ext_vector_type(16)));
typedef float  f32x4  __attribute__((ext_vector_type(4)));
typedef __bf16 bf16x8 __attribute__((ext_vector_type(8)));
typedef unsigned short ushort8v __attribute__((ext_vector_type(8)));

__device__ float          Tg[(size_t)M_ROWS * 16];   // T = X@L1, fp32
__device__ unsigned short L1t[16 * K_DIM];           // L1^T, bf16
__device__ unsigned short L2t[N_OUT * 16];           // L2^T, bf16

__device__ __forceinline__ unsigned short f2bf(float f) {
    __bf16 h = (__bf16)f;                       // native v_cvt (RNE)
    union { __bf16 h; unsigned short u; } v; v.h = h;
    return v.u;
}

// ------------------- tiny transposes: L1 -> L1t (bf16), L2 -> L2t (bf16)
__global__ __launch_bounds__(256) void lorap_kernel(
        const float* __restrict__ L1, const float* __restrict__ L2) {
    const int idx = blockIdx.x * 256 + threadIdx.x;
    if (idx < K_DIM) {                       // L1t, thread = one k
        const float4* lp = (const float4*)&L1[(size_t)idx * 16];
        float4 r0 = lp[0], r1 = lp[1], r2 = lp[2], r3 = lp[3];
        float v[16] = {r0.x, r0.y, r0.z, r0.w, r1.x, r1.y, r1.z, r1.w,
                       r2.x, r2.y, r2.z, r2.w, r3.x, r3.y, r3.z, r3.w};
        #pragma unroll
        for (int r = 0; r < 16; ++r)
            L1t[(size_t)r * K_DIM + idx] = f2bf(v[r]);
    } else {                                 // L2t, thread = one n
        const int n = idx - K_DIM;
        ushort8v a, b;
        #pragma unroll
        for (int r = 0; r < 8; ++r) a[r] = f2bf(L2[(size_t)r * N_OUT + n]);
        #pragma unroll
        for (int r = 0; r < 8; ++r) b[r] = f2bf(L2[(size_t)(r + 8) * N_OUT + n]);
        *(ushort8v*)&L2t[(size_t)n * 16]     = a;
        *(ushort8v*)&L2t[(size_t)n * 16 + 8] = b;
    }
}

// --------------- merged prep: cvt | wprep | xl1 (mutually independent parts)
__global__ __launch_bounds__(256) void prep_all_kernel(
        const float* __restrict__ X,    ushort8v* __restrict__ Xh,
        const float* __restrict__ Wnf4, const float* __restrict__ c1p,
        const float* __restrict__ c2,   unsigned short* __restrict__ Wt) {
    const int t = threadIdx.x;

    if (blockIdx.x < CVT_BLOCKS) {
        // ---- X fp32 -> bf16, 8 elems/thread
        size_t tid = (size_t)blockIdx.x * 256 + t;
        const float4* xp = (const float4*)X;
        float4 a = xp[tid * 2];
        float4 b = xp[tid * 2 + 1];
        ushort8v o;
        o[0] = f2bf(a.x); o[1] = f2bf(a.y); o[2] = f2bf(a.z); o[3] = f2bf(a.w);
        o[4] = f2bf(b.x); o[5] = f2bf(b.y); o[6] = f2bf(b.z); o[7] = f2bf(b.w);
        Xh[tid] = o;
        return;
    }

    if (blockIdx.x < CVT_BLOCKS + WP_BLOCKS) {
        // ---- W' = W_nf4*c1*c2, transposed store via LDS 64x64 tile
        __shared__ unsigned short tile[64][72];   // [n][k], pad 8 = 16B align
        const int wb = blockIdx.x - CVT_BLOCKS;
        const int n0 = (wb & 63) * 64;
        const int k0 = (wb >> 6) * 64;
        const float c1 = *c1p;

        #pragma unroll
        for (int i = 0; i < 4; ++i) {
            int idx = i * 1024 + t * 4;
            int k = idx >> 6, n4 = idx & 63;
            size_t g = (size_t)(k0 + k) * N_OUT + n0 + n4;
            float4 w = *(const float4*)&Wnf4[g];
            float4 s = *(const float4*)&c2[g];
            tile[n4    ][k] = f2bf(w.x * c1 * s.x);
            tile[n4 + 1][k] = f2bf(w.y * c1 * s.y);
            tile[n4 + 2][k] = f2bf(w.z * c1 * s.z);
            tile[n4 + 3][k] = f2bf(w.w * c1 * s.w);
        }
        __syncthreads();

        #pragma unroll
        for (int i = 0; i < 2; ++i) {
            int task = i * 256 + t;
            int n = task >> 3, k8 = (task & 7) * 8;
            ushort8v o = *(const ushort8v*)&tile[n][k8];
            *(ushort8v*)&Wt[(size_t)(n0 + n) * K_DIM + k0 + k8] = o;
        }
        return;
    }

    // ---- T = Xh @ L1 slice (reads fp32 X directly; L1t from lorap_kernel)
    {
        __shared__ float red[4][256];
        const int m0 = (blockIdx.x - CVT_BLOCKS - WP_BLOCKS) * 16;
        const int wv = t >> 6, lane = t & 63;
        const int l15 = lane & 15, l4 = lane >> 4;
        const float* ap = X + (size_t)(m0 + l15) * K_DIM + wv * 1024 + l4 * 8;
        const __bf16* bp = (const __bf16*)L1t + (size_t)l15 * K_DIM + wv * 1024 + l4 * 8;
        f32x4 acc = {};
        #pragma unroll 8
        for (int k = 0; k < 1024; k += 32) {
            float4 p0 = *(const float4*)(ap + k);
            float4 p1 = *(const float4*)(ap + k + 4);
            bf16x8 a;
            a[0] = (__bf16)p0.x; a[1] = (__bf16)p0.y;
            a[2] = (__bf16)p0.z; a[3] = (__bf16)p0.w;
            a[4] = (__bf16)p1.x; a[5] = (__bf16)p1.y;
            a[6] = (__bf16)p1.z; a[7] = (__bf16)p1.w;
            bf16x8 b = *(const bf16x8*)(bp + k);
            acc = __builtin_amdgcn_mfma_f32_16x16x32_bf16(a, b, acc, 0, 0, 0);
        }
        #pragma unroll
        for (int r = 0; r < 4; ++r) red[wv][(l4 * 4 + r) * 16 + l15] = acc[r];
        __syncthreads();
        if (wv == 0) {
            #pragma unroll
            for (int r = 0; r < 4; ++r) {
                int e = (l4 * 4 + r) * 16 + l15;
                Tg[(size_t)(m0 + l4 * 4 + r) * 16 + l15] =
                    red[0][e] + red[1][e] + red[2][e] + red[3][e];
            }
        }
    }
}

// ----------------------------------------------------------------- bf16 GEMM
// C[M][N] = A[M][K]*Bt[N][K]^T + T@L2t^T ; 128x128 tile, BK=64 (2x 32-wide
// staged buffers), 4 waves, 2 barriers per 64-K. R7/R8-verified body.
// m_base: M-quarter offset (kernel launched 4x, 2048 rows each).
#define COMPUTE(B) do { \
    bf16x8 af[2][2], bfr[2][2]; \
    _Pragma("unroll") for (int mt = 0; mt < 2; ++mt) \
      _Pragma("unroll") for (int ks = 0; ks < 2; ++ks) { \
        int row = wm + mt * 32 + l32; \
        int slot = (2 * ks + half) ^ rsw; \
        af[mt][ks] = *(const bf16x8*)(&As[B][0] + row * 32 + slot * 8); \
      } \
    _Pragma("unroll") for (int nt = 0; nt < 2; ++nt) \
      _Pragma("unroll") for (int ks = 0; ks < 2; ++ks) { \
        int row = wn + nt * 32 + l32; \
        int slot = (2 * ks + half) ^ rsw; \
        bfr[nt][ks] = *(const bf16x8*)(&Bs[B][0] + row * 32 + slot * 8); \
      } \
    _Pragma("unroll") for (int ks = 0; ks < 2; ++ks) \
      _Pragma("unroll") for (int mt = 0; mt < 2; ++mt) \
        _Pragma("unroll") for (int nt = 0; nt < 2; ++nt) \
          acc[mt][nt] = __builtin_amdgcn_mfma_f32_32x32x16_bf16( \
              af[mt][ks], bfr[nt][ks], acc[mt][nt], 0, 0, 0); \
} while (0)

__global__ __launch_bounds__(256) void gemm_bt_kernel(
        const __bf16* __restrict__ A, const __bf16* __restrict__ Bt,
        float* __restrict__ C, int m_base) {
    __shared__ __bf16 As[2][128 * 32];   // 16 KB
    __shared__ __bf16 Bs[2][128 * 32];   // 16 KB

    const int t    = threadIdx.x;
    const int w    = t >> 6;
    const int lane = t & 63;
    const int half = lane >> 5;       // 0..1
    const int l32  = lane & 31;

    const int m0   = m_base + blockIdx.y * 128;
    const int n0   = blockIdx.x * 128;

    const int wm   = (w >> 1) * 64;
    const int wn   = (w & 1) * 64;

    // staging source permutation: lane l -> row l>>2,
    // phys slot l&3 holds logical slot (l&3)^((l>>3)&3)
    const int srow = lane >> 2;
    const int scol = ((lane & 3) ^ ((lane >> 3) & 3)) * 8;
    // read-side swizzle: (row>>1)&3 with row = base32 + l32
    const int rsw = (l32 >> 1) & 3;

    f32x16 acc[2][2] = {};

    for (int kb = 0; kb < K_DIM; kb += 64) {
        __syncthreads();
        #pragma unroll
        for (int b = 0; b < 2; ++b) {
            #pragma unroll
            for (int j = 0; j < 2; ++j) {
                int row = w * 32 + j * 16 + srow;
                const __bf16* gp = A + (size_t)(m0 + row) * K_DIM + kb + b * 32 + scol;
                __builtin_amdgcn_global_load_lds(
                    (const __attribute__((address_space(1))) unsigned int*)gp,
                    (__attribute__((address_space(3))) unsigned int*)
                        (&As[b][0] + (w * 32 + j * 16) * 32),
                    16, 0, 0);
            }
            #pragma unroll
            for (int j = 0; j < 2; ++j) {
                int row = w * 32 + j * 16 + srow;
                const __bf16* gp = Bt + (size_t)(n0 + row) * K_DIM + kb + b * 32 + scol;
                __builtin_amdgcn_global_load_lds(
                    (const __attribute__((address_space(1))) unsigned int*)gp,
                    (__attribute__((address_space(3))) unsigned int*)
                        (&Bs[b][0] + (w * 32 + j * 16) * 32),
                    16, 0, 0);
            }
        }
        __syncthreads();

        COMPUTE(0);
        COMPUTE(1);
    }

    // ---- LoRA epilogue (verified in R5): acc += T(128x16) @ L2t^T, K=16.
    {
        bf16x8 afl[2], bfl[2];
        #pragma unroll
        for (int mt = 0; mt < 2; ++mt) {
            const float* tp = Tg + (size_t)(m0 + wm + mt * 32 + l32) * 16 + half * 8;
            float4 p0 = *(const float4*)tp;
            float4 p1 = *(const float4*)(tp + 4);
            afl[mt][0] = (__bf16)p0.x; afl[mt][1] = (__bf16)p0.y;
            afl[mt][2] = (__bf16)p0.z; afl[mt][3] = (__bf16)p0.w;
            afl[mt][4] = (__bf16)p1.x; afl[mt][5] = (__bf16)p1.y;
            afl[mt][6] = (__bf16)p1.z; afl[mt][7] = (__bf16)p1.w;
        }
        #pragma unroll
        for (int nt = 0; nt < 2; ++nt)
            bfl[nt] = *(const bf16x8*)((const __bf16*)L2t +
                        (size_t)(n0 + wn + nt * 32 + l32) * 16 + half * 8);
        #pragma unroll
        for (int mt = 0; mt < 2; ++mt)
            #pragma unroll
            for (int nt = 0; nt < 2; ++nt)
                acc[mt][nt] = __builtin_amdgcn_mfma_f32_32x32x16_bf16(
                    afl[mt], bfl[nt], acc[mt][nt], 0, 0, 0);
    }

    // epilogue: C/D 32x32 layout col=lane&31, row=(reg&3)+8*(reg>>2)+4*half
    #pragma unroll
    for (int mt = 0; mt < 2; ++mt)
        #pragma unroll
        for (int nt = 0; nt < 2; ++nt) {
            int col = n0 + wn + nt * 32 + l32;
            #pragma unroll
            for (int reg = 0; reg < 16; ++reg) {
                int row = m0 + wm + mt * 32 + (reg & 3) + 8 * (reg >> 2) + 4 * half;
                C[(size_t)row * N_OUT + col] = acc[mt][nt][reg];
            }
        }
}

extern "C" void kernel_launch(void* const* d_in, const int* in_sizes, int n_in,
                              void* d_out, int out_size, void* d_ws, size_t ws_size,
                              hipStream_t stream) {
    const float* X    = (const float*)d_in[0];
    const float* Wnf4 = (const float*)d_in[1];
    const float* c1   = (const float*)d_in[2];   // scalar
    const float* c2   = (const float*)d_in[3];
    const float* L1   = (const float*)d_in[4];
    const float* L2   = (const float*)d_in[5];
    float* Y = (float*)d_out;

    unsigned short* Xh = (unsigned short*)d_ws;                                       // 64 MB
    unsigned short* Wt = (unsigned short*)((char*)d_ws + (size_t)M_ROWS * K_DIM * 2); // 32 MB

    lorap_kernel<<<32, 256, 0, stream>>>(L1, L2);
    prep_all_kernel<<<PREP_BLOCKS, 256, 0, stream>>>(
        X, (ushort8v*)Xh, Wnf4, c1, c2, Wt);

    // GEMM in 4 M-quarters (512 blocks = 2 blocks/CU each: keeps cross-block
    // overlap; R9's 1 block/CU collapsed MfmaUtil 37->17).
    for (int q = 0; q < 4; ++q)
        gemm_bt_kernel<<<dim3(N_OUT / 128, 16), 256, 0, stream>>>(
            (const __bf16*)Xh, (const __bf16*)Wt, Y, q * 2048);
}

// Round 8
// 713.897 us; speedup vs baseline: 1.2745x; 1.0093x over previous
//
#include <hip/hip_runtime.h>

// QLORA: Y = X @ (W_nf4*c1*c2) + (X @ L1) @ L2
// M=8192, K=4096, N=4096, RANK=16.
// R11 changes vs R10:
//  - prep_all: persistent co-resident cohort of EXACTLY 2048 blocks (8/CU x
//    256 CU), mixed roles: 1280 cvt / 512 wprep / 256 xl1, each grid-striding
//    its own worklist. R10 counters showed prep latency-bound (HBM 25%,
//    VALU 3.4%, MfmaUtil 0.3%): 21K one-shot blocks in 3 sequential phase
//    waves, no overlap. Now all roles co-resident on every CU (streaming
//    hides xl1 MFMA latency), stride loops give cross-iteration MLP.
//  - xl1 K-split 4x (2048 units) + fp32 atomicAdd into Tg; Tg zeroed each
//    iteration by lorap_kernel (stream-ordered before prep_all) -> idempotent.
//  - GEMM: revert to measured-best M-halves (1024 blocks = 4/CU, 168us each
//    in R8). R10's quarter-split cost ~100us (residual arithmetic: quarters
//    ran ~105-115us at 2 blocks/CU).

#define M_ROWS 8192
#define K_DIM  4096
#define N_OUT  4096

#define CVT_UNITS 16384         // M*K/8/256
#define WP_UNITS  4096          // (N/64)*(K/64)
#define XL1_UNITS 2048          // (M/16) * 4 K-splits
#define NCVT 1280
#define NWP  512
#define NXL  256
#define PREP_GRID (NCVT + NWP + NXL)   // 2048 = 8 blocks/CU x 256 CU

typedef float  f32x16 __attribute__((ext_vector_type(16)));
typedef float  f32x4  __attribute__((ext_vector_type(4)));
typedef __bf16 bf16x8 __attribute__((ext_vector_type(8)));
typedef unsigned short ushort8v __attribute__((ext_vector_type(8)));

__device__ float          Tg[(size_t)M_ROWS * 16];   // T = X@L1, fp32 (atomic)
__device__ unsigned short L1t[16 * K_DIM];           // L1^T, bf16
__device__ unsigned short L2t[N_OUT * 16];           // L2^T, bf16

__device__ __forceinline__ unsigned short f2bf(float f) {
    __bf16 h = (__bf16)f;                       // native v_cvt (RNE)
    union { __bf16 h; unsigned short u; } v; v.h = h;
    return v.u;
}

// ---- lorap: zero Tg + transpose L1 -> L1t (bf16), L2 -> L2t (bf16)
__global__ __launch_bounds__(256) void lorap_kernel(
        const float* __restrict__ L1, const float* __restrict__ L2) {
    const int idx = blockIdx.x * 256 + threadIdx.x;   // 0..8191

    // zero Tg (8192 threads x 16 floats = 131072): atomic targets for xl1
    #pragma unroll
    for (int i = 0; i < 16; ++i) Tg[(size_t)idx * 16 + i] = 0.f;

    if (idx < K_DIM) {                       // L1t, thread = one k
        const float4* lp = (const float4*)&L1[(size_t)idx * 16];
        float4 r0 = lp[0], r1 = lp[1], r2 = lp[2], r3 = lp[3];
        float v[16] = {r0.x, r0.y, r0.z, r0.w, r1.x, r1.y, r1.z, r1.w,
                       r2.x, r2.y, r2.z, r2.w, r3.x, r3.y, r3.z, r3.w};
        #pragma unroll
        for (int r = 0; r < 16; ++r)
            L1t[(size_t)r * K_DIM + idx] = f2bf(v[r]);
    } else {                                 // L2t, thread = one n
        const int n = idx - K_DIM;
        ushort8v a, b;
        #pragma unroll
        for (int r = 0; r < 8; ++r) a[r] = f2bf(L2[(size_t)r * N_OUT + n]);
        #pragma unroll
        for (int r = 0; r < 8; ++r) b[r] = f2bf(L2[(size_t)(r + 8) * N_OUT + n]);
        *(ushort8v*)&L2t[(size_t)n * 16]     = a;
        *(ushort8v*)&L2t[(size_t)n * 16 + 8] = b;
    }
}

// ---- merged persistent prep: 2048 co-resident blocks, mixed roles
__global__ __launch_bounds__(256) void prep_all_kernel(
        const float* __restrict__ X,    ushort8v* __restrict__ Xh,
        const float* __restrict__ Wnf4, const float* __restrict__ c1p,
        const float* __restrict__ c2,   unsigned short* __restrict__ Wt) {
    const int t   = threadIdx.x;
    const int bid = blockIdx.x;

    if (bid < NCVT) {
        // ---- X fp32 -> bf16, stride loop (12-13 units/block, no syncs)
        for (int u = bid; u < CVT_UNITS; u += NCVT) {
            size_t tid = (size_t)u * 256 + t;
            const float4* xp = (const float4*)X;
            float4 a = xp[tid * 2];
            float4 b = xp[tid * 2 + 1];
            ushort8v o;
            o[0] = f2bf(a.x); o[1] = f2bf(a.y); o[2] = f2bf(a.z); o[3] = f2bf(a.w);
            o[4] = f2bf(b.x); o[5] = f2bf(b.y); o[6] = f2bf(b.z); o[7] = f2bf(b.w);
            Xh[tid] = o;
        }
        return;
    }

    if (bid < NCVT + NWP) {
        // ---- W' dequant + LDS transpose, 8 tiles/block (uniform: sync-safe)
        __shared__ unsigned short tile[64][72];   // pad 8 keeps 16B align
        const float c1 = *c1p;
        for (int wb = bid - NCVT; wb < WP_UNITS; wb += NWP) {
            const int n0 = (wb & 63) * 64;
            const int k0 = (wb >> 6) * 64;
            #pragma unroll
            for (int i = 0; i < 4; ++i) {
                int idx = i * 1024 + t * 4;
                int k = idx >> 6, n4 = idx & 63;
                size_t g = (size_t)(k0 + k) * N_OUT + n0 + n4;
                float4 w = *(const float4*)&Wnf4[g];
                float4 s = *(const float4*)&c2[g];
                tile[n4    ][k] = f2bf(w.x * c1 * s.x);
                tile[n4 + 1][k] = f2bf(w.y * c1 * s.y);
                tile[n4 + 2][k] = f2bf(w.z * c1 * s.z);
                tile[n4 + 3][k] = f2bf(w.w * c1 * s.w);
            }
            __syncthreads();
            #pragma unroll
            for (int i = 0; i < 2; ++i) {
                int task = i * 256 + t;
                int n = task >> 3, k8 = (task & 7) * 8;
                ushort8v o = *(const ushort8v*)&tile[n][k8];
                *(ushort8v*)&Wt[(size_t)(n0 + n) * K_DIM + k0 + k8] = o;
            }
            __syncthreads();
        }
        return;
    }

    // ---- T = X @ L1, K-split units, 8 units/block (uniform: sync-safe)
    {
        __shared__ float red[4][256];
        const int wv = t >> 6, lane = t & 63;
        const int l15 = lane & 15, l4 = lane >> 4;
        for (int u = bid - NCVT - NWP; u < XL1_UNITS; u += NXL) {
            const int m0 = (u >> 2) * 16;
            const int kb = (u & 3) * 1024 + wv * 256;
            const float* ap = X + (size_t)(m0 + l15) * K_DIM + kb + l4 * 8;
            const __bf16* bp = (const __bf16*)L1t + (size_t)l15 * K_DIM + kb + l4 * 8;
            f32x4 acc = {};
            #pragma unroll
            for (int k = 0; k < 256; k += 32) {
                float4 p0 = *(const float4*)(ap + k);
                float4 p1 = *(const float4*)(ap + k + 4);
                bf16x8 a;
                a[0] = (__bf16)p0.x; a[1] = (__bf16)p0.y;
                a[2] = (__bf16)p0.z; a[3] = (__bf16)p0.w;
                a[4] = (__bf16)p1.x; a[5] = (__bf16)p1.y;
                a[6] = (__bf16)p1.z; a[7] = (__bf16)p1.w;
                bf16x8 b = *(const bf16x8*)(bp + k);
                acc = __builtin_amdgcn_mfma_f32_16x16x32_bf16(a, b, acc, 0, 0, 0);
            }
            #pragma unroll
            for (int r = 0; r < 4; ++r) red[wv][(l4 * 4 + r) * 16 + l15] = acc[r];
            __syncthreads();
            if (wv == 0) {
                #pragma unroll
                for (int r = 0; r < 4; ++r) {
                    int e = (l4 * 4 + r) * 16 + l15;
                    atomicAdd(&Tg[(size_t)(m0 + l4 * 4 + r) * 16 + l15],
                              red[0][e] + red[1][e] + red[2][e] + red[3][e]);
                }
            }
            __syncthreads();
        }
    }
}

// ----------------------------------------------------------------- bf16 GEMM
// C[M][N] = A[M][K]*Bt[N][K]^T + T@L2t^T ; 128x128 tile, BK=64 (2x 32-wide
// staged buffers), 4 waves, 2 barriers per 64-K. R7/R8-verified body.
// m_base: M-half offset (kernel launched 2x, 4096 rows each -- R8 measured).
#define COMPUTE(B) do { \
    bf16x8 af[2][2], bfr[2][2]; \
    _Pragma("unroll") for (int mt = 0; mt < 2; ++mt) \
      _Pragma("unroll") for (int ks = 0; ks < 2; ++ks) { \
        int row = wm + mt * 32 + l32; \
        int slot = (2 * ks + half) ^ rsw; \
        af[mt][ks] = *(const bf16x8*)(&As[B][0] + row * 32 + slot * 8); \
      } \
    _Pragma("unroll") for (int nt = 0; nt < 2; ++nt) \
      _Pragma("unroll") for (int ks = 0; ks < 2; ++ks) { \
        int row = wn + nt * 32 + l32; \
        int slot = (2 * ks + half) ^ rsw; \
        bfr[nt][ks] = *(const bf16x8*)(&Bs[B][0] + row * 32 + slot * 8); \
      } \
    _Pragma("unroll") for (int ks = 0; ks < 2; ++ks) \
      _Pragma("unroll") for (int mt = 0; mt < 2; ++mt) \
        _Pragma("unroll") for (int nt = 0; nt < 2; ++nt) \
          acc[mt][nt] = __builtin_amdgcn_mfma_f32_32x32x16_bf16( \
              af[mt][ks], bfr[nt][ks], acc[mt][nt], 0, 0, 0); \
} while (0)

__global__ __launch_bounds__(256) void gemm_bt_kernel(
        const __bf16* __restrict__ A, const __bf16* __restrict__ Bt,
        float* __restrict__ C, int m_base) {
    __shared__ __bf16 As[2][128 * 32];   // 16 KB
    __shared__ __bf16 Bs[2][128 * 32];   // 16 KB

    const int t    = threadIdx.x;
    const int w    = t >> 6;
    const int lane = t & 63;
    const int half = lane >> 5;       // 0..1
    const int l32  = lane & 31;

    const int m0   = m_base + blockIdx.y * 128;
    const int n0   = blockIdx.x * 128;

    const int wm   = (w >> 1) * 64;
    const int wn   = (w & 1) * 64;

    // staging source permutation: lane l -> row l>>2,
    // phys slot l&3 holds logical slot (l&3)^((l>>3)&3)
    const int srow = lane >> 2;
    const int scol = ((lane & 3) ^ ((lane >> 3) & 3)) * 8;
    // read-side swizzle: (row>>1)&3 with row = base32 + l32
    const int rsw = (l32 >> 1) & 3;

    f32x16 acc[2][2] = {};

    for (int kb = 0; kb < K_DIM; kb += 64) {
        __syncthreads();
        #pragma unroll
        for (int b = 0; b < 2; ++b) {
            #pragma unroll
            for (int j = 0; j < 2; ++j) {
                int row = w * 32 + j * 16 + srow;
                const __bf16* gp = A + (size_t)(m0 + row) * K_DIM + kb + b * 32 + scol;
                __builtin_amdgcn_global_load_lds(
                    (const __attribute__((address_space(1))) unsigned int*)gp,
                    (__attribute__((address_space(3))) unsigned int*)
                        (&As[b][0] + (w * 32 + j * 16) * 32),
                    16, 0, 0);
            }
            #pragma unroll
            for (int j = 0; j < 2; ++j) {
                int row = w * 32 + j * 16 + srow;
                const __bf16* gp = Bt + (size_t)(n0 + row) * K_DIM + kb + b * 32 + scol;
                __builtin_amdgcn_global_load_lds(
                    (const __attribute__((address_space(1))) unsigned int*)gp,
                    (__attribute__((address_space(3))) unsigned int*)
                        (&Bs[b][0] + (w * 32 + j * 16) * 32),
                    16, 0, 0);
            }
        }
        __syncthreads();

        COMPUTE(0);
        COMPUTE(1);
    }

    // ---- LoRA epilogue (verified in R5): acc += T(128x16) @ L2t^T, K=16.
    {
        bf16x8 afl[2], bfl[2];
        #pragma unroll
        for (int mt = 0; mt < 2; ++mt) {
            const float* tp = Tg + (size_t)(m0 + wm + mt * 32 + l32) * 16 + half * 8;
            float4 p0 = *(const float4*)tp;
            float4 p1 = *(const float4*)(tp + 4);
            afl[mt][0] = (__bf16)p0.x; afl[mt][1] = (__bf16)p0.y;
            afl[mt][2] = (__bf16)p0.z; afl[mt][3] = (__bf16)p0.w;
            afl[mt][4] = (__bf16)p1.x; afl[mt][5] = (__bf16)p1.y;
            afl[mt][6] = (__bf16)p1.z; afl[mt][7] = (__bf16)p1.w;
        }
        #pragma unroll
        for (int nt = 0; nt < 2; ++nt)
            bfl[nt] = *(const bf16x8*)((const __bf16*)L2t +
                        (size_t)(n0 + wn + nt * 32 + l32) * 16 + half * 8);
        #pragma unroll
        for (int mt = 0; mt < 2; ++mt)
            #pragma unroll
            for (int nt = 0; nt < 2; ++nt)
                acc[mt][nt] = __builtin_amdgcn_mfma_f32_32x32x16_bf16(
                    afl[mt], bfl[nt], acc[mt][nt], 0, 0, 0);
    }

    // epilogue: C/D 32x32 layout col=lane&31, row=(reg&3)+8*(reg>>2)+4*half
    #pragma unroll
    for (int mt = 0; mt < 2; ++mt)
        #pragma unroll
        for (int nt = 0; nt < 2; ++nt) {
            int col = n0 + wn + nt * 32 + l32;
            #pragma unroll
            for (int reg = 0; reg < 16; ++reg) {
                int row = m0 + wm + mt * 32 + (reg & 3) + 8 * (reg >> 2) + 4 * half;
                C[(size_t)row * N_OUT + col] = acc[mt][nt][reg];
            }
        }
}

extern "C" void kernel_launch(void* const* d_in, const int* in_sizes, int n_in,
                              void* d_out, int out_size, void* d_ws, size_t ws_size,
                              hipStream_t stream) {
    const float* X    = (const float*)d_in[0];
    const float* Wnf4 = (const float*)d_in[1];
    const float* c1   = (const float*)d_in[2];   // scalar
    const float* c2   = (const float*)d_in[3];
    const float* L1   = (const float*)d_in[4];
    const float* L2   = (const float*)d_in[5];
    float* Y = (float*)d_out;

    unsigned short* Xh = (unsigned short*)d_ws;                                       // 64 MB
    unsigned short* Wt = (unsigned short*)((char*)d_ws + (size_t)M_ROWS * K_DIM * 2); // 32 MB

    lorap_kernel<<<32, 256, 0, stream>>>(L1, L2);        // zeros Tg + L1t/L2t
    prep_all_kernel<<<PREP_GRID, 256, 0, stream>>>(
        X, (ushort8v*)Xh, Wnf4, c1, c2, Wt);

    // GEMM in 2 M-halves (1024 blocks = 4/CU each; R8-measured 168us/half).
    gemm_bt_kernel<<<dim3(N_OUT / 128, 32), 256, 0, stream>>>(
        (const __bf16*)Xh, (const __bf16*)Wt, Y, 0);
    gemm_bt_kernel<<<dim3(N_OUT / 128, 32), 256, 0, stream>>>(
        (const __bf16*)Xh, (const __bf16*)Wt, Y, 4096);
}

// Round 9
// 636.274 us; speedup vs baseline: 1.4299x; 1.1220x over previous
//
#include <hip/hip_runtime.h>

// QLORA: Y = X @ (W_nf4*c1*c2) + (X @ L1) @ L2
// M=8192, K=4096, N=4096, RANK=16.
// R12 changes vs R11:
//  - Cohort reverted (R11: prep 150->193us, occupancy 59->37%; static role
//    split left a low-occupancy tail). Back to R10 one-shot prep blocks.
//  - EXPERIMENT: cvt role deleted; xl1 writes Xh as a side product (it
//    already streams X fp32 and holds the bf16-converted MFMA A-frag in
//    registers). Prep traffic 495->352MB, X read once. xl1 blocks dispatched
//    FIRST (512 long streamers co-resident with 4096 short wprep blocks).
//  - GEMM: back to measured-best M-halves (1024 blocks = 4/CU, 168us each,
//    R8/R10-verified body, natural 2D raster).

#define M_ROWS 8192
#define K_DIM  4096
#define N_OUT  4096
#define XL1_BLOCKS 512          // M/16, each: 16 rows x full K + Xh store
#define WP_BLOCKS  4096         // (N/64)*(K/64)

typedef float  f32x16 __attribute__((ext_vector_type(16)));
typedef float  f32x4  __attribute__((ext_vector_type(4)));
typedef __bf16 bf16x8 __attribute__((ext_vector_type(8)));
typedef unsigned short ushort8v __attribute__((ext_vector_type(8)));

__device__ float          Tg[(size_t)M_ROWS * 16];   // T = X@L1, fp32
__device__ unsigned short L1t[16 * K_DIM];           // L1^T, bf16
__device__ unsigned short L2t[N_OUT * 16];           // L2^T, bf16

__device__ __forceinline__ unsigned short f2bf(float f) {
    __bf16 h = (__bf16)f;                       // native v_cvt (RNE)
    union { __bf16 h; unsigned short u; } v; v.h = h;
    return v.u;
}

// ------------------- tiny transposes: L1 -> L1t (bf16), L2 -> L2t (bf16)
__global__ __launch_bounds__(256) void lorap_kernel(
        const float* __restrict__ L1, const float* __restrict__ L2) {
    const int idx = blockIdx.x * 256 + threadIdx.x;
    if (idx < K_DIM) {                       // L1t, thread = one k
        const float4* lp = (const float4*)&L1[(size_t)idx * 16];
        float4 r0 = lp[0], r1 = lp[1], r2 = lp[2], r3 = lp[3];
        float v[16] = {r0.x, r0.y, r0.z, r0.w, r1.x, r1.y, r1.z, r1.w,
                       r2.x, r2.y, r2.z, r2.w, r3.x, r3.y, r3.z, r3.w};
        #pragma unroll
        for (int r = 0; r < 16; ++r)
            L1t[(size_t)r * K_DIM + idx] = f2bf(v[r]);
    } else {                                 // L2t, thread = one n
        const int n = idx - K_DIM;
        ushort8v a, b;
        #pragma unroll
        for (int r = 0; r < 8; ++r) a[r] = f2bf(L2[(size_t)r * N_OUT + n]);
        #pragma unroll
        for (int r = 0; r < 8; ++r) b[r] = f2bf(L2[(size_t)(r + 8) * N_OUT + n]);
        *(ushort8v*)&L2t[(size_t)n * 16]     = a;
        *(ushort8v*)&L2t[(size_t)n * 16 + 8] = b;
    }
}

// --------------- merged prep: xl1+cvt (blocks 0..511) | wprep (512..4607)
__global__ __launch_bounds__(256) void prep_all_kernel(
        const float* __restrict__ X,    unsigned short* __restrict__ Xh,
        const float* __restrict__ Wnf4, const float* __restrict__ c1p,
        const float* __restrict__ c2,   unsigned short* __restrict__ Wt) {
    const int t = threadIdx.x;

    if (blockIdx.x < XL1_BLOCKS) {
        // ---- T = X @ L1 (16 rows, full K, 4-wave K-split) + Xh side-write.
        // Lane (l15,l4) holds X[m0+l15][kb+k+l4*8 ..+8] converted to bf16 as
        // the MFMA A-frag -> stored straight to Xh (exact 1-writer coverage).
        __shared__ float red[4][256];
        const int m0 = blockIdx.x * 16;
        const int wv = t >> 6, lane = t & 63;
        const int l15 = lane & 15, l4 = lane >> 4;
        const size_t rowoff = (size_t)(m0 + l15) * K_DIM + wv * 1024 + l4 * 8;
        const float* ap = X + rowoff;
        unsigned short* xp = Xh + rowoff;
        const __bf16* bp = (const __bf16*)L1t + (size_t)l15 * K_DIM + wv * 1024 + l4 * 8;
        f32x4 acc = {};
        #pragma unroll 8
        for (int k = 0; k < 1024; k += 32) {
            float4 p0 = *(const float4*)(ap + k);
            float4 p1 = *(const float4*)(ap + k + 4);
            bf16x8 a;
            a[0] = (__bf16)p0.x; a[1] = (__bf16)p0.y;
            a[2] = (__bf16)p0.z; a[3] = (__bf16)p0.w;
            a[4] = (__bf16)p1.x; a[5] = (__bf16)p1.y;
            a[6] = (__bf16)p1.z; a[7] = (__bf16)p1.w;
            *(bf16x8*)(xp + k) = a;                  // cvt fused: Xh store
            bf16x8 b = *(const bf16x8*)(bp + k);
            acc = __builtin_amdgcn_mfma_f32_16x16x32_bf16(a, b, acc, 0, 0, 0);
        }
        #pragma unroll
        for (int r = 0; r < 4; ++r) red[wv][(l4 * 4 + r) * 16 + l15] = acc[r];
        __syncthreads();
        if (wv == 0) {
            #pragma unroll
            for (int r = 0; r < 4; ++r) {
                int e = (l4 * 4 + r) * 16 + l15;
                Tg[(size_t)(m0 + l4 * 4 + r) * 16 + l15] =
                    red[0][e] + red[1][e] + red[2][e] + red[3][e];
            }
        }
        return;
    }

    // ---- W' = W_nf4*c1*c2, transposed store via LDS 64x64 tile (one-shot)
    {
        __shared__ unsigned short tile[64][72];   // [n][k], pad 8 = 16B align
        const int wb = blockIdx.x - XL1_BLOCKS;
        const int n0 = (wb & 63) * 64;
        const int k0 = (wb >> 6) * 64;
        const float c1 = *c1p;

        #pragma unroll
        for (int i = 0; i < 4; ++i) {
            int idx = i * 1024 + t * 4;
            int k = idx >> 6, n4 = idx & 63;
            size_t g = (size_t)(k0 + k) * N_OUT + n0 + n4;
            float4 w = *(const float4*)&Wnf4[g];
            float4 s = *(const float4*)&c2[g];
            tile[n4    ][k] = f2bf(w.x * c1 * s.x);
            tile[n4 + 1][k] = f2bf(w.y * c1 * s.y);
            tile[n4 + 2][k] = f2bf(w.z * c1 * s.z);
            tile[n4 + 3][k] = f2bf(w.w * c1 * s.w);
        }
        __syncthreads();

        #pragma unroll
        for (int i = 0; i < 2; ++i) {
            int task = i * 256 + t;
            int n = task >> 3, k8 = (task & 7) * 8;
            ushort8v o = *(const ushort8v*)&tile[n][k8];
            *(ushort8v*)&Wt[(size_t)(n0 + n) * K_DIM + k0 + k8] = o;
        }
    }
}

// ----------------------------------------------------------------- bf16 GEMM
// C[M][N] = A[M][K]*Bt[N][K]^T + T@L2t^T ; 128x128 tile, BK=64 (2x 32-wide
// staged buffers), 4 waves, 2 barriers per 64-K. R7/R8/R10-verified body.
// m_base: M-half offset (launched 2x, 4096 rows each -- R8-measured best).
#define COMPUTE(B) do { \
    bf16x8 af[2][2], bfr[2][2]; \
    _Pragma("unroll") for (int mt = 0; mt < 2; ++mt) \
      _Pragma("unroll") for (int ks = 0; ks < 2; ++ks) { \
        int row = wm + mt * 32 + l32; \
        int slot = (2 * ks + half) ^ rsw; \
        af[mt][ks] = *(const bf16x8*)(&As[B][0] + row * 32 + slot * 8); \
      } \
    _Pragma("unroll") for (int nt = 0; nt < 2; ++nt) \
      _Pragma("unroll") for (int ks = 0; ks < 2; ++ks) { \
        int row = wn + nt * 32 + l32; \
        int slot = (2 * ks + half) ^ rsw; \
        bfr[nt][ks] = *(const bf16x8*)(&Bs[B][0] + row * 32 + slot * 8); \
      } \
    _Pragma("unroll") for (int ks = 0; ks < 2; ++ks) \
      _Pragma("unroll") for (int mt = 0; mt < 2; ++mt) \
        _Pragma("unroll") for (int nt = 0; nt < 2; ++nt) \
          acc[mt][nt] = __builtin_amdgcn_mfma_f32_32x32x16_bf16( \
              af[mt][ks], bfr[nt][ks], acc[mt][nt], 0, 0, 0); \
} while (0)

__global__ __launch_bounds__(256) void gemm_bt_kernel(
        const __bf16* __restrict__ A, const __bf16* __restrict__ Bt,
        float* __restrict__ C, int m_base) {
    __shared__ __bf16 As[2][128 * 32];   // 16 KB
    __shared__ __bf16 Bs[2][128 * 32];   // 16 KB

    const int t    = threadIdx.x;
    const int w    = t >> 6;
    const int lane = t & 63;
    const int half = lane >> 5;       // 0..1
    const int l32  = lane & 31;

    const int m0   = m_base + blockIdx.y * 128;
    const int n0   = blockIdx.x * 128;

    const int wm   = (w >> 1) * 64;
    const int wn   = (w & 1) * 64;

    // staging source permutation: lane l -> row l>>2,
    // phys slot l&3 holds logical slot (l&3)^((l>>3)&3)
    const int srow = lane >> 2;
    const int scol = ((lane & 3) ^ ((lane >> 3) & 3)) * 8;
    // read-side swizzle: (row>>1)&3 with row = base32 + l32
    const int rsw = (l32 >> 1) & 3;

    f32x16 acc[2][2] = {};

    for (int kb = 0; kb < K_DIM; kb += 64) {
        __syncthreads();
        #pragma unroll
        for (int b = 0; b < 2; ++b) {
            #pragma unroll
            for (int j = 0; j < 2; ++j) {
                int row = w * 32 + j * 16 + srow;
                const __bf16* gp = A + (size_t)(m0 + row) * K_DIM + kb + b * 32 + scol;
                __builtin_amdgcn_global_load_lds(
                    (const __attribute__((address_space(1))) unsigned int*)gp,
                    (__attribute__((address_space(3))) unsigned int*)
                        (&As[b][0] + (w * 32 + j * 16) * 32),
                    16, 0, 0);
            }
            #pragma unroll
            for (int j = 0; j < 2; ++j) {
                int row = w * 32 + j * 16 + srow;
                const __bf16* gp = Bt + (size_t)(n0 + row) * K_DIM + kb + b * 32 + scol;
                __builtin_amdgcn_global_load_lds(
                    (const __attribute__((address_space(1))) unsigned int*)gp,
                    (__attribute__((address_space(3))) unsigned int*)
                        (&Bs[b][0] + (w * 32 + j * 16) * 32),
                    16, 0, 0);
            }
        }
        __syncthreads();

        COMPUTE(0);
        COMPUTE(1);
    }

    // ---- LoRA epilogue (verified in R5): acc += T(128x16) @ L2t^T, K=16.
    {
        bf16x8 afl[2], bfl[2];
        #pragma unroll
        for (int mt = 0; mt < 2; ++mt) {
            const float* tp = Tg + (size_t)(m0 + wm + mt * 32 + l32) * 16 + half * 8;
            float4 p0 = *(const float4*)tp;
            float4 p1 = *(const float4*)(tp + 4);
            afl[mt][0] = (__bf16)p0.x; afl[mt][1] = (__bf16)p0.y;
            afl[mt][2] = (__bf16)p0.z; afl[mt][3] = (__bf16)p0.w;
            afl[mt][4] = (__bf16)p1.x; afl[mt][5] = (__bf16)p1.y;
            afl[mt][6] = (__bf16)p1.z; afl[mt][7] = (__bf16)p1.w;
        }
        #pragma unroll
        for (int nt = 0; nt < 2; ++nt)
            bfl[nt] = *(const bf16x8*)((const __bf16*)L2t +
                        (size_t)(n0 + wn + nt * 32 + l32) * 16 + half * 8);
        #pragma unroll
        for (int mt = 0; mt < 2; ++mt)
            #pragma unroll
            for (int nt = 0; nt < 2; ++nt)
                acc[mt][nt] = __builtin_amdgcn_mfma_f32_32x32x16_bf16(
                    afl[mt], bfl[nt], acc[mt][nt], 0, 0, 0);
    }

    // epilogue: C/D 32x32 layout col=lane&31, row=(reg&3)+8*(reg>>2)+4*half
    #pragma unroll
    for (int mt = 0; mt < 2; ++mt)
        #pragma unroll
        for (int nt = 0; nt < 2; ++nt) {
            int col = n0 + wn + nt * 32 + l32;
            #pragma unroll
            for (int reg = 0; reg < 16; ++reg) {
                int row = m0 + wm + mt * 32 + (reg & 3) + 8 * (reg >> 2) + 4 * half;
                C[(size_t)row * N_OUT + col] = acc[mt][nt][reg];
            }
        }
}

extern "C" void kernel_launch(void* const* d_in, const int* in_sizes, int n_in,
                              void* d_out, int out_size, void* d_ws, size_t ws_size,
                              hipStream_t stream) {
    const float* X    = (const float*)d_in[0];
    const float* Wnf4 = (const float*)d_in[1];
    const float* c1   = (const float*)d_in[2];   // scalar
    const float* c2   = (const float*)d_in[3];
    const float* L1   = (const float*)d_in[4];
    const float* L2   = (const float*)d_in[5];
    float* Y = (float*)d_out;

    unsigned short* Xh = (unsigned short*)d_ws;                                       // 64 MB
    unsigned short* Wt = (unsigned short*)((char*)d_ws + (size_t)M_ROWS * K_DIM * 2); // 32 MB

    lorap_kernel<<<32, 256, 0, stream>>>(L1, L2);
    prep_all_kernel<<<XL1_BLOCKS + WP_BLOCKS, 256, 0, stream>>>(
        X, Xh, Wnf4, c1, c2, Wt);

    // GEMM in 2 M-halves (1024 blocks = 4/CU each; R8-measured 168us/half).
    gemm_bt_kernel<<<dim3(N_OUT / 128, 32), 256, 0, stream>>>(
        (const __bf16*)Xh, (const __bf16*)Wt, Y, 0);
    gemm_bt_kernel<<<dim3(N_OUT / 128, 32), 256, 0, stream>>>(
        (const __bf16*)Xh, (const __bf16*)Wt, Y, 4096);
}